// Round 6
// baseline (495.196 us; speedup 1.0000x reference)
//
#include <hip/hip_runtime.h>
#include <stdint.h>

#define NN 50000
#define EE 800000
#define ET 850000
#define INC 128
#define HID 256
#define OUTC 128
#define NB ((NN + 255) / 256)   // 196 scan blocks

typedef __attribute__((ext_vector_type(4))) float f32x4;
typedef __attribute__((ext_vector_type(8))) short s16x8;
typedef __attribute__((ext_vector_type(4))) short s16x4;

static __device__ __forceinline__ float b2f(unsigned short u){
  union { float f; unsigned int i; } v; v.i = ((unsigned int)u) << 16; return v.f;
}
static __device__ __forceinline__ unsigned short f2b(float f){
  union { float f; unsigned int i; } v; v.f = f;
  unsigned int r = v.i + 0x7FFFu + ((v.i >> 16) & 1u);
  return (unsigned short)(r >> 16);
}

// ---------------- CSR build ----------------
__global__ void k_degree(const int* __restrict__ ei, int* __restrict__ cnt){
  int e = blockIdx.x * 256 + threadIdx.x;
  if (e >= ET) return;
  int d = (e < EE) ? ei[EE + e] : (e - EE);
  atomicAdd(&cnt[d], 1);
}

// per-block exclusive scan + block sums; zeroes cnt for k_scatter reuse
__global__ void k_blockscan(int* __restrict__ cnt, int* __restrict__ off,
                            int* __restrict__ bsum){
  __shared__ int s[256];
  int b = blockIdx.x, tid = threadIdx.x;
  int i = b * 256 + tid;
  int v = (i < NN) ? cnt[i] : 0;
  if (i < NN) cnt[i] = 0;
  s[tid] = v; __syncthreads();
  #pragma unroll
  for (int o = 1; o < 256; o <<= 1){
    int t = (tid >= o) ? s[tid - o] : 0; __syncthreads();
    s[tid] += t; __syncthreads();
  }
  if (i < NN) off[i] = s[tid] - v;
  if (tid == 255) bsum[b] = s[255];
}

__global__ void k_scanb(const int* __restrict__ bsum, int* __restrict__ bbase){
  __shared__ int s[256];
  int tid = threadIdx.x;
  int v = (tid < NB) ? bsum[tid] : 0;
  s[tid] = v; __syncthreads();
  #pragma unroll
  for (int o = 1; o < 256; o <<= 1){
    int t = (tid >= o) ? s[tid - o] : 0; __syncthreads();
    s[tid] += t; __syncthreads();
  }
  if (tid < NB) bbase[tid] = s[tid] - v;
}

__global__ void k_addback(int* __restrict__ off, const int* __restrict__ bbase){
  int b = blockIdx.x, tid = threadIdx.x;
  int i = b * 256 + tid;
  if (i < NN) off[i] += bbase[b];
  if (i == 0) off[NN] = ET;
}

__global__ void k_scatter(const int* __restrict__ ei, const int* __restrict__ off,
                          int* __restrict__ cnt, int* __restrict__ ssrc){
  int e = blockIdx.x * 256 + threadIdx.x;
  if (e >= ET) return;
  int s, d;
  if (e < EE){ s = ei[e]; d = ei[EE + e]; } else { s = e - EE; d = s; }
  int p = off[d] + atomicAdd(&cnt[d], 1);
  ssrc[p] = s;
}

// ---------------- all 3 W transposes in one launch ----------------
__global__ void k_transposeAll(const float* __restrict__ W1, const float* __restrict__ W2,
                               const float* __restrict__ W3, unsigned short* __restrict__ T1,
                               unsigned short* __restrict__ T2, unsigned short* __restrict__ T3){
  int b = blockIdx.x;
  const float* W; unsigned short* WT; int K, base;
  if (b < 128)      { W = W1; WT = T1; K = 128; base = 0; }
  else if (b < 384) { W = W2; WT = T2; K = 256; base = 128; }
  else              { W = W3; WT = T3; K = 256; base = 384; }
  int idx = (b - base) * 256 + threadIdx.x;   // < K*256
  int k = idx >> 8, c = idx & 255;
  WT[c * K + k] = f2b(W[idx]);
}

// ---------------- fused MFMA GEMM (64x256 tile) + alpha epilogue ----------------
// Single barrier per K-step, double-buffered A in LDS, next-tile reg prefetch.
// B fragments read directly from L2-resident WT [256,K].
template<bool AF32>
__global__ __launch_bounds__(256) void k_gemm_fused(const void* __restrict__ Av,
    const unsigned short* __restrict__ WT,
    const float* __restrict__ a_src, const float* __restrict__ a_dst,
    unsigned short* __restrict__ C, float* __restrict__ as_, float* __restrict__ ad_,
    int M, int K){
  __shared__ unsigned short sMem[64 * 258];              // 33024 B
  unsigned short (*sA)[64][72]  = (unsigned short (*)[64][72])sMem;   // 2 x 9216 B
  unsigned short (*sC)[258] = (unsigned short (*)[258])sMem;
  int tid = threadIdx.x;
  int wave = tid >> 6, lane = tid & 63;
  int bm0 = blockIdx.x * 64;
  int wc0 = wave * 64;
  int r_ = (tid >> 2) & 63;                 // not used; keep compiler calm
  (void)r_;
  f32x4 acc[4][4];
  #pragma unroll
  for (int i = 0; i < 4; i++)
    #pragma unroll
    for (int j = 0; j < 4; j++) acc[i][j] = (f32x4){0.f, 0.f, 0.f, 0.f};

  s16x8 regs[2];
  int li0 = tid, li1 = tid + 256;
  int r0 = li0 >> 3, kb0 = (li0 & 7) * 8;
  int r1 = li1 >> 3, kb1 = (li1 & 7) * 8;

  auto ldA = [&](int k0){
    #pragma unroll
    for (int i = 0; i < 2; i++){
      int rr = i ? r1 : r0, kb = i ? kb1 : kb0;
      int gr = bm0 + rr;
      if constexpr (AF32){
        const float* A = (const float*)Av;
        unsigned short t[8] = {0,0,0,0,0,0,0,0};
        if (gr < M){
          const float4* p = (const float4*)(A + (size_t)gr * K + k0 + kb);
          float4 v0 = p[0], v1 = p[1];
          t[0]=f2b(v0.x); t[1]=f2b(v0.y); t[2]=f2b(v0.z); t[3]=f2b(v0.w);
          t[4]=f2b(v1.x); t[5]=f2b(v1.y); t[6]=f2b(v1.z); t[7]=f2b(v1.w);
        }
        regs[i] = *(s16x8*)t;
      } else {
        const unsigned short* A = (const unsigned short*)Av;
        s16x8 v = (s16x8){0,0,0,0,0,0,0,0};
        if (gr < M) v = *(const s16x8*)(A + (size_t)gr * K + k0 + kb);
        regs[i] = v;
      }
    }
  };
  auto stA = [&](int buf){
    *(s16x8*)&sA[buf][r0][kb0] = regs[0];
    *(s16x8*)&sA[buf][r1][kb1] = regs[1];
  };

  int T = K >> 6;
  ldA(0); stA(0);
  __syncthreads();
  for (int t = 0; t < T; t++){
    int k0 = t << 6;
    if (t + 1 < T) ldA(k0 + 64);            // prefetch next A tile (HBM under MFMA)
    int cur = t & 1;
    #pragma unroll
    for (int kk = 0; kk < 64; kk += 32){
      int kl = kk + (lane >> 4) * 8;
      s16x8 af[4], bf[4];
      #pragma unroll
      for (int ni = 0; ni < 4; ni++)
        bf[ni] = *(const s16x8*)(WT + (size_t)(wc0 + ni * 16 + (lane & 15)) * K + k0 + kl);
      #pragma unroll
      for (int mi = 0; mi < 4; mi++) af[mi] = *(const s16x8*)&sA[cur][mi * 16 + (lane & 15)][kl];
      #pragma unroll
      for (int mi = 0; mi < 4; mi++)
        #pragma unroll
        for (int ni = 0; ni < 4; ni++)
          acc[mi][ni] = __builtin_amdgcn_mfma_f32_16x16x32_bf16(af[mi], bf[ni], acc[mi][ni], 0, 0, 0);
    }
    if (t + 1 < T) stA(cur ^ 1);            // write other buffer (no WAR: barrier below)
    __syncthreads();
  }

  // epilogue: C tile -> LDS + global, per-head alpha dot
  #pragma unroll
  for (int mi = 0; mi < 4; mi++){
    #pragma unroll
    for (int ni = 0; ni < 4; ni++){
      int col = wc0 + ni * 16 + (lane & 15);
      int rb = mi * 16 + (lane >> 4) * 4;
      #pragma unroll
      for (int r = 0; r < 4; r++){
        int row = rb + r;
        unsigned short us = f2b(acc[mi][ni][r]);
        sC[row][col] = us;
        if (bm0 + row < M) C[(size_t)(bm0 + row) * HID + col] = us;
      }
    }
  }
  __syncthreads();
  {
    int q = wave, r = lane;
    float ps = 0.f, pd = 0.f;
    #pragma unroll 8
    for (int d = 0; d < 64; d++){
      float hv = b2f(sC[r][q * 64 + d]);
      ps += hv * a_src[q * 64 + d];
      pd += hv * a_dst[q * 64 + d];
    }
    if (bm0 + r < M){
      as_[(size_t)(bm0 + r) * 4 + q] = ps;
      ad_[(size_t)(bm0 + r) * 4 + q] = pd;
    }
  }
}

// ---------------- per-(edge,head) unnormalized weights ----------------
// one wave per dst node; lane = (edge j within pass)*4 + head
__global__ __launch_bounds__(256) void k_edgew(const int* __restrict__ off,
    const int* __restrict__ ssrc, const float* __restrict__ as_,
    const float* __restrict__ ad_, float* __restrict__ wbuf){
  int gid = blockIdx.x * 256 + threadIdx.x;
  int wid = gid >> 6, lane = gid & 63;
  if (wid >= NN) return;
  int start = off[wid], end = off[wid + 1];
  int hh = lane & 3, jl = lane >> 2;
  float adv = ad_[(size_t)wid * 4 + hh];
  for (int base = start; base < end; base += 16){
    int j = base + jl;
    if (j < end){
      int s = ssrc[j];
      float lg = as_[(size_t)s * 4 + hh] + adv;
      lg = lg > 0.f ? lg : 0.2f * lg;               // leaky_relu(0.2)
      wbuf[(size_t)j * 4 + hh] = __expf(fminf(lg, 60.f));
    }
  }
}

// ---------------- aggregation: 4-edge unroll, precomputed weights ----------------
__global__ __launch_bounds__(256) void k_aggregate(const int* __restrict__ off,
    const int* __restrict__ ssrc, const float* __restrict__ wbuf,
    const unsigned short* __restrict__ h, const float* __restrict__ bias,
    unsigned short* __restrict__ out){
  int gid = blockIdx.x * 256 + threadIdx.x;
  int wid = gid >> 6, lane = gid & 63;
  if (wid >= NN) return;
  int start = off[wid], end = off[wid + 1], e1 = end - 1;
  int hq = lane >> 4;
  const float* wb = wbuf + hq;
  float s0 = 0.f, s1 = 0.f, s2 = 0.f, s3 = 0.f;
  f32x4 A = {0,0,0,0}, B = {0,0,0,0}, Cc = {0,0,0,0}, D = {0,0,0,0};
  int p = start;
  // prologue: rows p..p+3 (clamped), idx p+4..p+7 (clamped)
  int j0 = ssrc[p];
  int j1 = ssrc[min(p + 1, e1)], j2 = ssrc[min(p + 2, e1)], j3 = ssrc[min(p + 3, e1)];
  s16x4 r0 = *(const s16x4*)(h + (size_t)j0 * HID + lane * 4);
  s16x4 r1 = *(const s16x4*)(h + (size_t)j1 * HID + lane * 4);
  s16x4 r2 = *(const s16x4*)(h + (size_t)j2 * HID + lane * 4);
  s16x4 r3 = *(const s16x4*)(h + (size_t)j3 * HID + lane * 4);
  int j4 = ssrc[min(p + 4, e1)], j5 = ssrc[min(p + 5, e1)];
  int j6 = ssrc[min(p + 6, e1)], j7 = ssrc[min(p + 7, e1)];

  for (; p + 3 < end; p += 4){
    int t0 = ssrc[min(p + 8, e1)],  t1 = ssrc[min(p + 9, e1)];
    int t2 = ssrc[min(p + 10, e1)], t3 = ssrc[min(p + 11, e1)];
    s16x4 u0 = *(const s16x4*)(h + (size_t)j4 * HID + lane * 4);
    s16x4 u1 = *(const s16x4*)(h + (size_t)j5 * HID + lane * 4);
    s16x4 u2 = *(const s16x4*)(h + (size_t)j6 * HID + lane * 4);
    s16x4 u3 = *(const s16x4*)(h + (size_t)j7 * HID + lane * 4);
    float w0 = wb[(size_t)p * 4],       w1 = wb[(size_t)(p + 1) * 4];
    float w2 = wb[(size_t)(p + 2) * 4], w3 = wb[(size_t)(p + 3) * 4];
    s0 += w0; s1 += w1; s2 += w2; s3 += w3;
    #pragma unroll
    for (int c = 0; c < 4; c++){
      A[c]  += w0 * b2f((unsigned short)r0[c]);
      B[c]  += w1 * b2f((unsigned short)r1[c]);
      Cc[c] += w2 * b2f((unsigned short)r2[c]);
      D[c]  += w3 * b2f((unsigned short)r3[c]);
    }
    j4 = t0; j5 = t1; j6 = t2; j7 = t3;
    r0 = u0; r1 = u1; r2 = u2; r3 = u3;
  }
  int rem = end - p;                                   // 0..3
  if (rem > 0){ float w = wb[(size_t)p * 4]; s0 += w;
    #pragma unroll
    for (int c = 0; c < 4; c++) A[c]  += w * b2f((unsigned short)r0[c]); }
  if (rem > 1){ float w = wb[(size_t)(p + 1) * 4]; s1 += w;
    #pragma unroll
    for (int c = 0; c < 4; c++) B[c]  += w * b2f((unsigned short)r1[c]); }
  if (rem > 2){ float w = wb[(size_t)(p + 2) * 4]; s2 += w;
    #pragma unroll
    for (int c = 0; c < 4; c++) Cc[c] += w * b2f((unsigned short)r2[c]); }

  float inv = 1.f / (s0 + s1 + s2 + s3 + 1e-16f);
  float4 bv = *(const float4*)(bias + lane * 4);
  float o0 = (A[0] + B[0] + Cc[0] + D[0]) * inv + bv.x;
  float o1 = (A[1] + B[1] + Cc[1] + D[1]) * inv + bv.y;
  float o2 = (A[2] + B[2] + Cc[2] + D[2]) * inv + bv.z;
  float o3 = (A[3] + B[3] + Cc[3] + D[3]) * inv + bv.w;
  o0 = o0 > 0.f ? o0 : (__expf(o0) - 1.f);
  o1 = o1 > 0.f ? o1 : (__expf(o1) - 1.f);
  o2 = o2 > 0.f ? o2 : (__expf(o2) - 1.f);
  o3 = o3 > 0.f ? o3 : (__expf(o3) - 1.f);
  s16x4 ov;
  ov[0] = (short)f2b(o0); ov[1] = (short)f2b(o1);
  ov[2] = (short)f2b(o2); ov[3] = (short)f2b(o3);
  *(s16x4*)(out + (size_t)wid * HID + lane * 4) = ov;
}

// ---------------- mean pool + head ----------------
__global__ void k_pool(const unsigned short* __restrict__ X, float* __restrict__ pool){
  int c = threadIdx.x;             // 256
  float acc = 0.f;
  for (int n = blockIdx.x; n < NN; n += gridDim.x) acc += b2f(X[(size_t)n * HID + c]);
  atomicAdd(&pool[c], acc);
}

__global__ void k_head(const float* __restrict__ pool, const float* __restrict__ hW,
                       const float* __restrict__ hb, float* __restrict__ outp){
  int o = threadIdx.x;             // 128
  float acc = hb[o];
  const float invN = 1.f / (float)NN;
  for (int c = 0; c < HID; c++) acc += pool[c] * invN * hW[c * OUTC + o];
  outp[o] = acc;
}

extern "C" void kernel_launch(void* const* d_in, const int* in_sizes, int n_in,
                              void* d_out, int out_size, void* d_ws, size_t ws_size,
                              hipStream_t stream){
  const float* x  = (const float*)d_in[0];
  const int* ei   = (const int*)d_in[1];
  const float* W[3]   = {(const float*)d_in[2],  (const float*)d_in[6],  (const float*)d_in[10]};
  const float* Asr[3] = {(const float*)d_in[3],  (const float*)d_in[7],  (const float*)d_in[11]};
  const float* Adt[3] = {(const float*)d_in[4],  (const float*)d_in[8],  (const float*)d_in[12]};
  const float* B[3]   = {(const float*)d_in[5],  (const float*)d_in[9],  (const float*)d_in[13]};
  const float* hW = (const float*)d_in[14];
  const float* hb = (const float*)d_in[15];

  char* w = (char*)d_ws; size_t o = 0;
  auto alloc = [&](size_t b) -> void* { void* p = w + o; o = (o + b + 255) & ~(size_t)255; return p; };
  int* cnt  = (int*)alloc((size_t)NN * 4);
  int* off  = (int*)alloc((size_t)(NN + 1) * 4);
  int* ssrc = (int*)alloc((size_t)ET * 4);
  int* bsum = (int*)alloc((size_t)NB * 4);
  int* bbase= (int*)alloc((size_t)NB * 4);
  unsigned short* hbuf = (unsigned short*)alloc((size_t)NN * HID * 2);
  float* as_ = (float*)alloc((size_t)NN * 4 * 4);
  float* ad_ = (float*)alloc((size_t)NN * 4 * 4);
  unsigned short* X0 = (unsigned short*)alloc((size_t)NN * HID * 2);
  unsigned short* X1 = (unsigned short*)alloc((size_t)NN * HID * 2);
  unsigned short* WT1 = (unsigned short*)alloc((size_t)INC * HID * 2);
  unsigned short* WT2 = (unsigned short*)alloc((size_t)HID * HID * 2);
  unsigned short* WT3 = (unsigned short*)alloc((size_t)HID * HID * 2);
  float* wbuf = (float*)alloc((size_t)ET * 4 * 4);
  float* pool = (float*)alloc(256 * 4);

  hipMemsetAsync(cnt, 0, (size_t)NN * 4, stream);
  hipMemsetAsync(pool, 0, 256 * 4, stream);
  k_degree<<<(ET + 255) / 256, 256, 0, stream>>>(ei, cnt);
  k_blockscan<<<NB, 256, 0, stream>>>(cnt, off, bsum);
  k_scanb<<<1, 256, 0, stream>>>(bsum, bbase);
  k_addback<<<NB, 256, 0, stream>>>(off, bbase);
  k_scatter<<<(ET + 255) / 256, 256, 0, stream>>>(ei, off, cnt, ssrc);
  k_transposeAll<<<640, 256, 0, stream>>>(W[0], W[1], W[2], WT1, WT2, WT3);

  const unsigned short* WTs[3] = {WT1, WT2, WT3};
  unsigned short* outbuf[3] = {X0, X1, X0};
  int Ks[3] = {INC, HID, HID};
  const void* Ain = (const void*)x;
  int gB = (NN + 63) / 64;
  int gW = (NN * 64 + 255) / 256;
  for (int l = 0; l < 3; l++){
    if (l == 0) k_gemm_fused<true ><<<gB, 256, 0, stream>>>(Ain, WTs[l], Asr[l], Adt[l], hbuf, as_, ad_, NN, Ks[l]);
    else        k_gemm_fused<false><<<gB, 256, 0, stream>>>(Ain, WTs[l], Asr[l], Adt[l], hbuf, as_, ad_, NN, Ks[l]);
    k_edgew<<<gW, 256, 0, stream>>>(off, ssrc, as_, ad_, wbuf);
    k_aggregate<<<gW, 256, 0, stream>>>(off, ssrc, wbuf, hbuf, B[l], outbuf[l]);
    Ain = (const void*)outbuf[l];
  }
  k_pool<<<256, 256, 0, stream>>>(X0, pool);
  k_head<<<1, 128, 0, stream>>>(pool, hW, hb, (float*)d_out);
}

// Round 7
// 417.968 us; speedup vs baseline: 1.1848x; 1.1848x over previous
//
#include <hip/hip_runtime.h>
#include <stdint.h>

#define NN 50000
#define EE 800000
#define ET 850000
#define INC 128
#define HID 256
#define OUTC 128
#define NB ((NN + 255) / 256)   // 196 scan blocks

typedef __attribute__((ext_vector_type(4))) float f32x4;
typedef __attribute__((ext_vector_type(8))) short s16x8;
typedef __attribute__((ext_vector_type(4))) short s16x4;

static __device__ __forceinline__ float b2f(unsigned short u){
  union { float f; unsigned int i; } v; v.i = ((unsigned int)u) << 16; return v.f;
}
static __device__ __forceinline__ unsigned short f2b(float f){
  union { float f; unsigned int i; } v; v.f = f;
  unsigned int r = v.i + 0x7FFFu + ((v.i >> 16) & 1u);
  return (unsigned short)(r >> 16);
}

// ---------------- CSR build ----------------
__global__ void k_degree(const int* __restrict__ ei, int* __restrict__ cnt){
  int e = blockIdx.x * 256 + threadIdx.x;
  if (e >= ET) return;
  int d = (e < EE) ? ei[EE + e] : (e - EE);
  atomicAdd(&cnt[d], 1);
}

// per-block exclusive scan + block sums; zeroes cnt for k_scatter reuse
__global__ void k_blockscan(int* __restrict__ cnt, int* __restrict__ off,
                            int* __restrict__ bsum){
  __shared__ int s[256];
  int b = blockIdx.x, tid = threadIdx.x;
  int i = b * 256 + tid;
  int v = (i < NN) ? cnt[i] : 0;
  if (i < NN) cnt[i] = 0;
  s[tid] = v; __syncthreads();
  #pragma unroll
  for (int o = 1; o < 256; o <<= 1){
    int t = (tid >= o) ? s[tid - o] : 0; __syncthreads();
    s[tid] += t; __syncthreads();
  }
  if (i < NN) off[i] = s[tid] - v;
  if (tid == 255) bsum[b] = s[255];
}

__global__ void k_scanb(const int* __restrict__ bsum, int* __restrict__ bbase){
  __shared__ int s[256];
  int tid = threadIdx.x;
  int v = (tid < NB) ? bsum[tid] : 0;
  s[tid] = v; __syncthreads();
  #pragma unroll
  for (int o = 1; o < 256; o <<= 1){
    int t = (tid >= o) ? s[tid - o] : 0; __syncthreads();
    s[tid] += t; __syncthreads();
  }
  if (tid < NB) bbase[tid] = s[tid] - v;
}

__global__ void k_addback(int* __restrict__ off, const int* __restrict__ bbase){
  int b = blockIdx.x, tid = threadIdx.x;
  int i = b * 256 + tid;
  if (i < NN) off[i] += bbase[b];
  if (i == 0) off[NN] = ET;
}

__global__ void k_scatter(const int* __restrict__ ei, const int* __restrict__ off,
                          int* __restrict__ cnt, int* __restrict__ ssrc){
  int e = blockIdx.x * 256 + threadIdx.x;
  if (e >= ET) return;
  int s, d;
  if (e < EE){ s = ei[e]; d = ei[EE + e]; } else { s = e - EE; d = s; }
  int p = off[d] + atomicAdd(&cnt[d], 1);
  ssrc[p] = s;
}

// ---------------- all 3 W transposes in one launch ----------------
__global__ void k_transposeAll(const float* __restrict__ W1, const float* __restrict__ W2,
                               const float* __restrict__ W3, unsigned short* __restrict__ T1,
                               unsigned short* __restrict__ T2, unsigned short* __restrict__ T3){
  int b = blockIdx.x;
  const float* W; unsigned short* WT; int K, base;
  if (b < 128)      { W = W1; WT = T1; K = 128; base = 0; }
  else if (b < 384) { W = W2; WT = T2; K = 256; base = 128; }
  else              { W = W3; WT = T3; K = 256; base = 384; }
  int idx = (b - base) * 256 + threadIdx.x;   // < K*256
  int k = idx >> 8, c = idx & 255;
  WT[c * K + k] = f2b(W[idx]);
}

// ---------------- fused MFMA GEMM (64x256 tile) + alpha epilogue ----------------
// Single barrier per K-step, double-buffered A in LDS, next-tile reg prefetch.
// B fragments read directly from L2-resident WT [256,K].
template<bool AF32>
__global__ __launch_bounds__(256) void k_gemm_fused(const void* __restrict__ Av,
    const unsigned short* __restrict__ WT,
    const float* __restrict__ a_src, const float* __restrict__ a_dst,
    unsigned short* __restrict__ C, float* __restrict__ as_, float* __restrict__ ad_,
    int M, int K){
  __shared__ unsigned short sMem[64 * 258];              // 33024 B
  unsigned short (*sA)[64][72]  = (unsigned short (*)[64][72])sMem;   // 2 x 9216 B
  unsigned short (*sC)[258] = (unsigned short (*)[258])sMem;
  int tid = threadIdx.x;
  int wave = tid >> 6, lane = tid & 63;
  int bm0 = blockIdx.x * 64;
  int wc0 = wave * 64;
  f32x4 acc[4][4];
  #pragma unroll
  for (int i = 0; i < 4; i++)
    #pragma unroll
    for (int j = 0; j < 4; j++) acc[i][j] = (f32x4){0.f, 0.f, 0.f, 0.f};

  s16x8 regs[2];
  int li0 = tid, li1 = tid + 256;
  int r0 = li0 >> 3, kb0 = (li0 & 7) * 8;
  int r1 = li1 >> 3, kb1 = (li1 & 7) * 8;

  auto ldA = [&](int k0){
    #pragma unroll
    for (int i = 0; i < 2; i++){
      int rr = i ? r1 : r0, kb = i ? kb1 : kb0;
      int gr = bm0 + rr;
      if constexpr (AF32){
        const float* A = (const float*)Av;
        unsigned short t[8] = {0,0,0,0,0,0,0,0};
        if (gr < M){
          const float4* p = (const float4*)(A + (size_t)gr * K + k0 + kb);
          float4 v0 = p[0], v1 = p[1];
          t[0]=f2b(v0.x); t[1]=f2b(v0.y); t[2]=f2b(v0.z); t[3]=f2b(v0.w);
          t[4]=f2b(v1.x); t[5]=f2b(v1.y); t[6]=f2b(v1.z); t[7]=f2b(v1.w);
        }
        regs[i] = *(s16x8*)t;
      } else {
        const unsigned short* A = (const unsigned short*)Av;
        s16x8 v = (s16x8){0,0,0,0,0,0,0,0};
        if (gr < M) v = *(const s16x8*)(A + (size_t)gr * K + k0 + kb);
        regs[i] = v;
      }
    }
  };
  auto stA = [&](int buf){
    *(s16x8*)&sA[buf][r0][kb0] = regs[0];
    *(s16x8*)&sA[buf][r1][kb1] = regs[1];
  };

  int T = K >> 6;
  ldA(0); stA(0);
  __syncthreads();
  for (int t = 0; t < T; t++){
    int k0 = t << 6;
    if (t + 1 < T) ldA(k0 + 64);            // prefetch next A tile (HBM under MFMA)
    int cur = t & 1;
    #pragma unroll
    for (int kk = 0; kk < 64; kk += 32){
      int kl = kk + (lane >> 4) * 8;
      s16x8 af[4], bf[4];
      #pragma unroll
      for (int ni = 0; ni < 4; ni++)
        bf[ni] = *(const s16x8*)(WT + (size_t)(wc0 + ni * 16 + (lane & 15)) * K + k0 + kl);
      #pragma unroll
      for (int mi = 0; mi < 4; mi++) af[mi] = *(const s16x8*)&sA[cur][mi * 16 + (lane & 15)][kl];
      #pragma unroll
      for (int mi = 0; mi < 4; mi++)
        #pragma unroll
        for (int ni = 0; ni < 4; ni++)
          acc[mi][ni] = __builtin_amdgcn_mfma_f32_16x16x32_bf16(af[mi], bf[ni], acc[mi][ni], 0, 0, 0);
    }
    if (t + 1 < T) stA(cur ^ 1);            // other buffer; barrier below orders it
    __syncthreads();
  }

  // epilogue: C tile -> LDS + global, per-head alpha dot
  #pragma unroll
  for (int mi = 0; mi < 4; mi++){
    #pragma unroll
    for (int ni = 0; ni < 4; ni++){
      int col = wc0 + ni * 16 + (lane & 15);
      int rb = mi * 16 + (lane >> 4) * 4;
      #pragma unroll
      for (int r = 0; r < 4; r++){
        int row = rb + r;
        unsigned short us = f2b(acc[mi][ni][r]);
        sC[row][col] = us;
        if (bm0 + row < M) C[(size_t)(bm0 + row) * HID + col] = us;
      }
    }
  }
  __syncthreads();
  {
    int q = wave, r = lane;
    float ps = 0.f, pd = 0.f;
    #pragma unroll 8
    for (int d = 0; d < 64; d++){
      float hv = b2f(sC[r][q * 64 + d]);
      ps += hv * a_src[q * 64 + d];
      pd += hv * a_dst[q * 64 + d];
    }
    if (bm0 + r < M){
      as_[(size_t)(bm0 + r) * 4 + q] = ps;
      ad_[(size_t)(bm0 + r) * 4 + q] = pd;
    }
  }
}

// ---------------- aggregation: inline weights, 4-edge unroll, 1-iter load slack ----------------
// One wave per dst node; lane -> channels 4*lane..4*lane+3, head = lane>>4.
// No online max (logits O(1), upper clamp 60; softmax shift-invariant, f32 can't overflow).
__global__ __launch_bounds__(256) void k_aggregate(const int* __restrict__ off,
    const int* __restrict__ ssrc, const float* __restrict__ as_, const float* __restrict__ ad_,
    const unsigned short* __restrict__ h, const float* __restrict__ bias,
    unsigned short* __restrict__ out){
  int gid = blockIdx.x * 256 + threadIdx.x;
  int wid = gid >> 6, lane = gid & 63;
  if (wid >= NN) return;
  int start = off[wid], end = off[wid + 1], e1 = end - 1;
  int hq = lane >> 4;
  float ad2 = ad_[(size_t)wid * 4 + hq];
  float sA_ = 0.f, sB_ = 0.f;
  f32x4 A = {0,0,0,0}, B = {0,0,0,0}, Cc = {0,0,0,0}, D = {0,0,0,0};

  int p = start;
  // current set: edges p..p+3 (clamped); next indices p+4..p+7
  int j0 = ssrc[p];
  int j1 = ssrc[min(p + 1, e1)], j2 = ssrc[min(p + 2, e1)], j3 = ssrc[min(p + 3, e1)];
  int j4 = ssrc[min(p + 4, e1)], j5 = ssrc[min(p + 5, e1)];
  int j6 = ssrc[min(p + 6, e1)], j7 = ssrc[min(p + 7, e1)];
  s16x4 r0 = *(const s16x4*)(h + (size_t)j0 * HID + lane * 4);
  s16x4 r1 = *(const s16x4*)(h + (size_t)j1 * HID + lane * 4);
  s16x4 r2 = *(const s16x4*)(h + (size_t)j2 * HID + lane * 4);
  s16x4 r3 = *(const s16x4*)(h + (size_t)j3 * HID + lane * 4);
  float a0 = as_[(size_t)j0 * 4 + hq], a1 = as_[(size_t)j1 * 4 + hq];
  float a2 = as_[(size_t)j2 * 4 + hq], a3 = as_[(size_t)j3 * 4 + hq];

  for (; p + 3 < end; p += 4){
    // prefetch next iteration's rows + as_ (consumers one iteration away)
    s16x4 u0 = *(const s16x4*)(h + (size_t)j4 * HID + lane * 4);
    s16x4 u1 = *(const s16x4*)(h + (size_t)j5 * HID + lane * 4);
    s16x4 u2 = *(const s16x4*)(h + (size_t)j6 * HID + lane * 4);
    s16x4 u3 = *(const s16x4*)(h + (size_t)j7 * HID + lane * 4);
    float b0 = as_[(size_t)j4 * 4 + hq], b1 = as_[(size_t)j5 * 4 + hq];
    float b2 = as_[(size_t)j6 * 4 + hq], b3 = as_[(size_t)j7 * 4 + hq];
    int t0 = ssrc[min(p + 8, e1)],  t1 = ssrc[min(p + 9, e1)];
    int t2 = ssrc[min(p + 10, e1)], t3 = ssrc[min(p + 11, e1)];
    // compute current 4 edges
    float l0 = a0 + ad2; l0 = l0 > 0.f ? l0 : 0.2f * l0;
    float l1 = a1 + ad2; l1 = l1 > 0.f ? l1 : 0.2f * l1;
    float l2 = a2 + ad2; l2 = l2 > 0.f ? l2 : 0.2f * l2;
    float l3 = a3 + ad2; l3 = l3 > 0.f ? l3 : 0.2f * l3;
    float w0 = __expf(fminf(l0, 60.f)), w1 = __expf(fminf(l1, 60.f));
    float w2 = __expf(fminf(l2, 60.f)), w3 = __expf(fminf(l3, 60.f));
    sA_ += w0 + w2; sB_ += w1 + w3;
    #pragma unroll
    for (int c = 0; c < 4; c++){
      A[c]  += w0 * b2f((unsigned short)r0[c]);
      B[c]  += w1 * b2f((unsigned short)r1[c]);
      Cc[c] += w2 * b2f((unsigned short)r2[c]);
      D[c]  += w3 * b2f((unsigned short)r3[c]);
    }
    j0 = j4; j1 = j5; j2 = j6; j3 = j7;
    j4 = t0; j5 = t1; j6 = t2; j7 = t3;
    r0 = u0; r1 = u1; r2 = u2; r3 = u3;
    a0 = b0; a1 = b1; a2 = b2; a3 = b3;
  }
  int rem = end - p;                                   // 0..3
  if (rem > 0){
    float l = a0 + ad2; l = l > 0.f ? l : 0.2f * l;
    float w = __expf(fminf(l, 60.f)); sA_ += w;
    #pragma unroll
    for (int c = 0; c < 4; c++) A[c]  += w * b2f((unsigned short)r0[c]);
  }
  if (rem > 1){
    float l = a1 + ad2; l = l > 0.f ? l : 0.2f * l;
    float w = __expf(fminf(l, 60.f)); sB_ += w;
    #pragma unroll
    for (int c = 0; c < 4; c++) B[c]  += w * b2f((unsigned short)r1[c]);
  }
  if (rem > 2){
    float l = a2 + ad2; l = l > 0.f ? l : 0.2f * l;
    float w = __expf(fminf(l, 60.f)); sA_ += w;
    #pragma unroll
    for (int c = 0; c < 4; c++) Cc[c] += w * b2f((unsigned short)r2[c]);
  }

  float inv = 1.f / (sA_ + sB_ + 1e-16f);
  float4 bv = *(const float4*)(bias + lane * 4);
  float o0 = (A[0] + B[0] + Cc[0] + D[0]) * inv + bv.x;
  float o1 = (A[1] + B[1] + Cc[1] + D[1]) * inv + bv.y;
  float o2 = (A[2] + B[2] + Cc[2] + D[2]) * inv + bv.z;
  float o3 = (A[3] + B[3] + Cc[3] + D[3]) * inv + bv.w;
  o0 = o0 > 0.f ? o0 : (__expf(o0) - 1.f);
  o1 = o1 > 0.f ? o1 : (__expf(o1) - 1.f);
  o2 = o2 > 0.f ? o2 : (__expf(o2) - 1.f);
  o3 = o3 > 0.f ? o3 : (__expf(o3) - 1.f);
  s16x4 ov;
  ov[0] = (short)f2b(o0); ov[1] = (short)f2b(o1);
  ov[2] = (short)f2b(o2); ov[3] = (short)f2b(o3);
  *(s16x4*)(out + (size_t)wid * HID + lane * 4) = ov;
}

// ---------------- mean pool + head ----------------
__global__ __launch_bounds__(256) void k_pool(const unsigned short* __restrict__ X,
                                              float* __restrict__ pool){
  int b = blockIdx.x, c = threadIdx.x;
  int n0 = b * 64, n1 = min(n0 + 64, NN);
  float acc = 0.f;
  for (int n = n0; n < n1; n++) acc += b2f(X[(size_t)n * HID + c]);
  atomicAdd(&pool[c], acc);
}

__global__ void k_head(const float* __restrict__ pool, const float* __restrict__ hW,
                       const float* __restrict__ hb, float* __restrict__ outp){
  int o = threadIdx.x;             // 128
  float acc = hb[o];
  const float invN = 1.f / (float)NN;
  for (int c = 0; c < HID; c++) acc += pool[c] * invN * hW[c * OUTC + o];
  outp[o] = acc;
}

extern "C" void kernel_launch(void* const* d_in, const int* in_sizes, int n_in,
                              void* d_out, int out_size, void* d_ws, size_t ws_size,
                              hipStream_t stream){
  const float* x  = (const float*)d_in[0];
  const int* ei   = (const int*)d_in[1];
  const float* W[3]   = {(const float*)d_in[2],  (const float*)d_in[6],  (const float*)d_in[10]};
  const float* Asr[3] = {(const float*)d_in[3],  (const float*)d_in[7],  (const float*)d_in[11]};
  const float* Adt[3] = {(const float*)d_in[4],  (const float*)d_in[8],  (const float*)d_in[12]};
  const float* B[3]   = {(const float*)d_in[5],  (const float*)d_in[9],  (const float*)d_in[13]};
  const float* hW = (const float*)d_in[14];
  const float* hb = (const float*)d_in[15];

  char* w = (char*)d_ws; size_t o = 0;
  auto alloc = [&](size_t b) -> void* { void* p = w + o; o = (o + b + 255) & ~(size_t)255; return p; };
  int* cnt  = (int*)alloc((size_t)NN * 4);
  int* off  = (int*)alloc((size_t)(NN + 1) * 4);
  int* ssrc = (int*)alloc((size_t)ET * 4);
  int* bsum = (int*)alloc((size_t)NB * 4);
  int* bbase= (int*)alloc((size_t)NB * 4);
  unsigned short* hbuf = (unsigned short*)alloc((size_t)NN * HID * 2);
  float* as_ = (float*)alloc((size_t)NN * 4 * 4);
  float* ad_ = (float*)alloc((size_t)NN * 4 * 4);
  unsigned short* X0 = (unsigned short*)alloc((size_t)NN * HID * 2);
  unsigned short* X1 = (unsigned short*)alloc((size_t)NN * HID * 2);
  unsigned short* WT1 = (unsigned short*)alloc((size_t)INC * HID * 2);
  unsigned short* WT2 = (unsigned short*)alloc((size_t)HID * HID * 2);
  unsigned short* WT3 = (unsigned short*)alloc((size_t)HID * HID * 2);
  float* pool = (float*)alloc(256 * 4);

  hipMemsetAsync(cnt, 0, (size_t)NN * 4, stream);
  hipMemsetAsync(pool, 0, 256 * 4, stream);
  k_degree<<<(ET + 255) / 256, 256, 0, stream>>>(ei, cnt);
  k_blockscan<<<NB, 256, 0, stream>>>(cnt, off, bsum);
  k_scanb<<<1, 256, 0, stream>>>(bsum, bbase);
  k_addback<<<NB, 256, 0, stream>>>(off, bbase);
  k_scatter<<<(ET + 255) / 256, 256, 0, stream>>>(ei, off, cnt, ssrc);
  k_transposeAll<<<640, 256, 0, stream>>>(W[0], W[1], W[2], WT1, WT2, WT3);

  const unsigned short* WTs[3] = {WT1, WT2, WT3};
  unsigned short* outbuf[3] = {X0, X1, X0};
  int Ks[3] = {INC, HID, HID};
  const void* Ain = (const void*)x;
  int gB = (NN + 63) / 64;
  int gW = (NN * 64 + 255) / 256;
  for (int l = 0; l < 3; l++){
    if (l == 0) k_gemm_fused<true ><<<gB, 256, 0, stream>>>(Ain, WTs[l], Asr[l], Adt[l], hbuf, as_, ad_, NN, Ks[l]);
    else        k_gemm_fused<false><<<gB, 256, 0, stream>>>(Ain, WTs[l], Asr[l], Adt[l], hbuf, as_, ad_, NN, Ks[l]);
    k_aggregate<<<gW, 256, 0, stream>>>(off, ssrc, as_, ad_, hbuf, B[l], outbuf[l]);
    Ain = (const void*)outbuf[l];
  }
  k_pool<<<gB, 256, 0, stream>>>(X0, pool);
  k_head<<<1, 128, 0, stream>>>(pool, hW, hb, (float*)d_out);
}